// Round 1
// baseline (1733.279 us; speedup 1.0000x reference)
//
#include <hip/hip_runtime.h>
#include <cstdint>
#include <cstddef>

#define N_NODES_C 50000
#define N_EDGES_C 1600000
#define N_GRAPHS_C 128
#define EDGE_DIM_C 43
#define IN_DIM_C 35
#define HDIM_C 128

typedef _Float16 f16x8 __attribute__((ext_vector_type(8)));
typedef float f32x4 __attribute__((ext_vector_type(4)));

__device__ __forceinline__ float fast_tanh(float x) {
    float xc = fminf(9.0f, fmaxf(-9.0f, x));
    float t = __expf(2.0f * xc);
    return (t - 1.0f) * __builtin_amdgcn_rcpf(t + 1.0f);
}

// ---------------- CSR build ----------------

__global__ __launch_bounds__(256) void hist_kernel(const int* __restrict__ src,
                                                   int* __restrict__ cnt) {
    int i = blockIdx.x * 256 + threadIdx.x;
    if (i < N_EDGES_C) atomicAdd(&cnt[src[i]], 1);
}

// single-array scan: rowptr (edge CSR); work = copy for the scatter pass
__global__ __launch_bounds__(1024) void scan_kernel(const int* __restrict__ cnt,
                                                    int* __restrict__ rowptr,
                                                    int* __restrict__ work) {
    __shared__ int wsum[16];
    __shared__ int carry;
    int t = threadIdx.x;
    int lane = t & 63, wid = t >> 6;
    if (t == 0) carry = 0;
    __syncthreads();
    for (int base = 0; base < N_NODES_C; base += 4096) {
        int i0 = base + t * 4;
        int v[4];
        #pragma unroll
        for (int j = 0; j < 4; ++j) {
            int i = i0 + j;
            v[j] = (i < N_NODES_C) ? cnt[i] : 0;
        }
        int pv[4];
        pv[0] = 0;
        #pragma unroll
        for (int j = 1; j < 4; ++j) pv[j] = pv[j-1] + v[j-1];
        int tot = pv[3] + v[3];
        int x = tot;
        #pragma unroll
        for (int off = 1; off < 64; off <<= 1) {
            int xx = __shfl_up(x, off, 64);
            if (lane >= off) x += xx;
        }
        if (lane == 63) wsum[wid] = x;
        __syncthreads();
        if (wid == 0) {
            int wa = (lane < 16) ? wsum[lane] : 0;
            #pragma unroll
            for (int off = 1; off < 16; off <<= 1) {
                int aa = __shfl_up(wa, off, 64);
                if (lane >= off) wa += aa;
            }
            if (lane < 16) wsum[lane] = wa;
        }
        __syncthreads();
        int ex = carry + (wid ? wsum[wid - 1] : 0) + x - tot;
        #pragma unroll
        for (int j = 0; j < 4; ++j) {
            int i = i0 + j;
            if (i < N_NODES_C) {
                int rv = ex + pv[j];
                rowptr[i] = rv; work[i] = rv;
            }
        }
        int totAll = wsum[15];
        __syncthreads();
        if (t == 0) carry += totAll;
        __syncthreads();
    }
    if (t == 0) rowptr[N_NODES_C] = carry;
}

// builds eord: edge ids sorted by (src node, arrival order) — CSR order
__global__ __launch_bounds__(256) void scatter_kernel(const int* __restrict__ src,
                                                      int* __restrict__ work,
                                                      int* __restrict__ eord) {
    int i = blockIdx.x * 256 + threadIdx.x;
    if (i < N_EDGES_C) {
        int s = src[i];
        int pos = atomicAdd(&work[s], 1);
        eord[pos] = i;
    }
}

// merged: graph bounds (binary search) + per-node meta {deg, rowptr}
__global__ __launch_bounds__(256) void graph_misc(const int* __restrict__ rowptr,
                                                  const int* __restrict__ batch,
                                                  int2* __restrict__ nmeta,
                                                  int* __restrict__ grp) {
    int i = blockIdx.x * 256 + threadIdx.x;
    if (i < N_NODES_C) {
        int rp = rowptr[i];
        int deg = rowptr[i + 1] - rp;
        nmeta[i] = make_int2(deg, rp);
    }
    if (i <= N_GRAPHS_C) {
        int lo = 0, hi = N_NODES_C;
        while (lo < hi) {
            int mid = (lo + hi) >> 1;
            if (batch[mid] < i) lo = mid + 1; else hi = mid;
        }
        grp[i] = lo;
    }
}

// STREAMING f32->f16 conversion in EDGE ORDER: fully coalesced both sides.
// Row = 48 halfs (96 B, 16B-aligned); cols 43..47 zeroed.
__global__ __launch_bounds__(256) void ea2h(const float* __restrict__ EA,
                                            _Float16* __restrict__ EAh) {
    int t = threadIdx.x;
    int e = blockIdx.x * 64 + (t >> 2);
    int q = t & 3;
    if (e >= N_EDGES_C) return;
    const float* pe = EA + (size_t)e * EDGE_DIM_C;
    unsigned int pk[6];
    #pragma unroll
    for (int jj = 0; jj < 6; ++jj) {
        int c0 = q * 12 + 2 * jj;
        float v0 = (c0 < EDGE_DIM_C) ? pe[c0] : 0.0f;
        float v1 = (c0 + 1 < EDGE_DIM_C) ? pe[c0 + 1] : 0.0f;
        unsigned short h0 = __builtin_bit_cast(unsigned short, (_Float16)v0);
        unsigned short h1 = __builtin_bit_cast(unsigned short, (_Float16)v1);
        pk[jj] = (unsigned int)h0 | ((unsigned int)h1 << 16);
    }
    unsigned int* outp = (unsigned int*)(EAh + (size_t)e * 48 + q * 12);
    *(uint2*)(outp)     = make_uint2(pk[0], pk[1]);
    *(uint2*)(outp + 2) = make_uint2(pk[2], pk[3]);
    *(uint2*)(outp + 4) = make_uint2(pk[4], pk[5]);
}

// ---------------- Node GEMM (Base = A@Wx.T+bn ; Root = tanh(A@Wr.T+br)) ----------------

#define BKN 32
__global__ __launch_bounds__(256) void node_gemm(
    const float* __restrict__ A, int K,
    const float* __restrict__ Wn, int ldn, const float* __restrict__ bn,
    const float* __restrict__ Wr, const float* __restrict__ br,
    float* __restrict__ Base, float* __restrict__ Root)
{
    __shared__ float At[BKN][64];
    __shared__ float Bw[BKN][128];
    int t = threadIdx.x;
    int z = blockIdx.y;
    const float* W = z ? Wr : Wn;
    int ldW = z ? K : ldn;
    const float* bias = z ? br : bn;
    float* Out = z ? Root : Base;

    int m0 = blockIdx.x * 64;
    int tn4 = (t % 32) * 4;
    int tm8 = (t / 32) * 8;
    float acc[8][4];
    #pragma unroll
    for (int a = 0; a < 8; a++)
        #pragma unroll
        for (int b = 0; b < 4; b++) acc[a][b] = 0.0f;

    int nkc = (K + BKN - 1) / BKN;
    for (int c = 0; c < nkc; c++) {
        int kc = c * BKN;
        {
            int m_l = t >> 2;
            int q = t & 3;
            int m = m0 + m_l;
            #pragma unroll
            for (int ii = 0; ii < 8; ii++) {
                int kk = q * 8 + ii;
                int k = kc + kk;
                float v = 0.0f;
                if (m < N_NODES_C && k < K) v = A[(size_t)m * K + k];
                At[kk][m_l] = v;
            }
        }
        {
            int j = t % 128;
            int kg2 = t / 128;
            #pragma unroll
            for (int ii = 0; ii < 16; ii++) {
                int kk = kg2 * 16 + ii;
                int k = kc + kk;
                float v = 0.0f;
                if (k < K) v = W[(size_t)j * ldW + k];
                Bw[kk][j] = v;
            }
        }
        __syncthreads();
        #pragma unroll
        for (int kk = 0; kk < BKN; kk++) {
            float a[8], b[4];
            #pragma unroll
            for (int mi = 0; mi < 8; mi++) a[mi] = At[kk][tm8 + mi];
            #pragma unroll
            for (int ni = 0; ni < 4; ni++) b[ni] = Bw[kk][tn4 + ni];
            #pragma unroll
            for (int mi = 0; mi < 8; mi++)
                #pragma unroll
                for (int ni = 0; ni < 4; ni++)
                    acc[mi][ni] = fmaf(a[mi], b[ni], acc[mi][ni]);
        }
        __syncthreads();
    }

    float4 bv = *(const float4*)&bias[tn4];
    #pragma unroll
    for (int mi = 0; mi < 8; mi++) {
        int m = m0 + tm8 + mi;
        if (m < N_NODES_C) {
            float4 o;
            o.x = acc[mi][0] + bv.x;
            o.y = acc[mi][1] + bv.y;
            o.z = acc[mi][2] + bv.z;
            o.w = acc[mi][3] + bv.w;
            if (z) { o.x = fast_tanh(o.x); o.y = fast_tanh(o.y); o.z = fast_tanh(o.z); o.w = fast_tanh(o.w); }
            *(float4*)&Out[(size_t)m * HDIM_C + tn4] = o;
        }
    }
}

// ---------------- MFMA edge conv: wave-per-node, gather A-fragments via eord ----------------
// A-fragment layout for mfma_f32_16x16x32_f16: lane l15 = row, quad*8 = k-offset.
// Rows gathered directly from EAh (f16 edge-order, L3-resident) via eord; no permuted copy.

__global__ __launch_bounds__(256) void edge_mfma(
    const _Float16* __restrict__ EAh, const int* __restrict__ eord,
    const int2* __restrict__ nmeta,
    const float* __restrict__ Base, const float* __restrict__ Root,
    const float* __restrict__ Wfull, int colOff, int ldW,
    float* __restrict__ Hout)
{
    int t = threadIdx.x;
    int lane = t & 63, wid = t >> 6;
    int l15 = lane & 15, quad = lane >> 4;

    // B fragments: weights held in VGPRs for the whole kernel
    f16x8 bf[8][2];
    #pragma unroll
    for (int nt = 0; nt < 8; ++nt) {
        const float* wr = Wfull + (size_t)(nt * 16 + l15) * ldW + colOff;
        #pragma unroll
        for (int kt = 0; kt < 2; ++kt) {
            f16x8 b;
            #pragma unroll
            for (int j = 0; j < 8; ++j) {
                int k = kt * 32 + quad * 8 + j;
                float v = (k < EDGE_DIM_C) ? wr[k] : 0.0f;
                b[j] = (_Float16)v;
            }
            bf[nt][kt] = b;
        }
    }

    bool useA1 = (quad < 2);
    int off0 = quad * 8;                 // halfs, k 0..31
    int off1 = 32 + ((quad & 1) * 8);    // halfs, k 32..47 (quads 0,1)

    int nstride = gridDim.x * 4;
    for (int n = blockIdx.x * 4 + wid; n < N_NODES_C; n += nstride) {
        int2 nm = nmeta[n];
        int deg = nm.x, rp = nm.y;
        const float* bp = Base + (size_t)n * HDIM_C;
        float bv[8];
        #pragma unroll
        for (int nt = 0; nt < 8; ++nt) bv[nt] = bp[nt * 16 + l15];
        float cs[8];
        #pragma unroll
        for (int nt = 0; nt < 8; ++nt) cs[nt] = 0.0f;

        int ngr = (deg + 15) >> 4;
        int rbase = quad * 4;
        if (ngr > 0) {
            f16x8 zz8 = {};
            f16x8 a0 = zz8, a1 = zz8;
            // gather group 0
            if (l15 < deg) {
                int e0 = eord[rp + l15];
                const _Float16* ap = EAh + (size_t)e0 * 48;
                a0 = *(const f16x8*)(ap + off0);
                if (useA1) a1 = *(const f16x8*)(ap + off1);
            }
            for (int gi = 0; gi < ngr; ++gi) {
                // prefetch next group's rows before consuming current
                f16x8 n0 = zz8, n1 = zz8;
                int rn = (gi + 1) * 16 + l15;
                if (rn < deg) {
                    int en = eord[rp + rn];
                    const _Float16* ap = EAh + (size_t)en * 48;
                    n0 = *(const f16x8*)(ap + off0);
                    if (useA1) n1 = *(const f16x8*)(ap + off1);
                }
                int valid = deg - gi * 16; if (valid > 16) valid = 16;
                f32x4 acc[8];
                #pragma unroll
                for (int nt = 0; nt < 8; ++nt) {
                    f32x4 zz = {0.f, 0.f, 0.f, 0.f};
                    acc[nt] = __builtin_amdgcn_mfma_f32_16x16x32_f16(a0, bf[nt][0], zz, 0, 0, 0);
                    acc[nt] = __builtin_amdgcn_mfma_f32_16x16x32_f16(a1, bf[nt][1], acc[nt], 0, 0, 0);
                }
                #pragma unroll
                for (int nt = 0; nt < 8; ++nt) {
                    #pragma unroll
                    for (int r = 0; r < 4; ++r) {
                        float v = fast_tanh(acc[nt][r] + bv[nt]);
                        cs[nt] += (rbase + r < valid) ? v : 0.0f;
                    }
                }
                a0 = n0; a1 = n1;
            }
        }
        #pragma unroll
        for (int nt = 0; nt < 8; ++nt) {
            cs[nt] += __shfl_xor(cs[nt], 16, 64);
            cs[nt] += __shfl_xor(cs[nt], 32, 64);
        }
        float v0, v1;
        if (quad == 0)      { v0 = cs[0]; v1 = cs[1]; }
        else if (quad == 1) { v0 = cs[2]; v1 = cs[3]; }
        else if (quad == 2) { v0 = cs[4]; v1 = cs[5]; }
        else                { v0 = cs[6]; v1 = cs[7]; }
        int c0 = quad * 32 + l15;
        size_t rowb = (size_t)n * HDIM_C;
        Hout[rowb + c0]      = Root[rowb + c0] + v0;
        Hout[rowb + c0 + 16] = Root[rowb + c0 + 16] + v1;
    }
}

// ---------------- Gate MLP as tiled GEMM: 64 nodes/block, 128->64->32->1 ----------------

__global__ __launch_bounds__(256) void gate_kernel(
    const float* __restrict__ h,
    const float* __restrict__ Wg1, const float* __restrict__ bg1,
    const float* __restrict__ Wg2, const float* __restrict__ bg2,
    const float* __restrict__ Wg3, const float* __restrict__ bg3,
    float* __restrict__ gate)
{
    __shared__ float Ht[128][65];
    __shared__ float G1[64][65];
    __shared__ float G2[32][65];
    int t = threadIdx.x;
    int m0 = blockIdx.x * 64;
    #pragma unroll
    for (int ii = 0; ii < 32; ++ii) {
        int flat = ii * 256 + t;
        int k = flat & 127, m = flat >> 7;
        float v = (m0 + m < N_NODES_C) ? h[(size_t)(m0 + m) * HDIM_C + k] : 0.0f;
        Ht[k][m] = v;
    }
    __syncthreads();
    int m = t & 63, slab = t >> 6;
    {
        float a[16];
        #pragma unroll
        for (int jj = 0; jj < 16; ++jj) a[jj] = bg1[slab * 16 + jj];
        for (int k = 0; k < 128; ++k) {
            float hv = Ht[k][m];
            #pragma unroll
            for (int jj = 0; jj < 16; ++jj)
                a[jj] = fmaf(Wg1[(size_t)(slab * 16 + jj) * 128 + k], hv, a[jj]);
        }
        #pragma unroll
        for (int jj = 0; jj < 16; ++jj) G1[slab * 16 + jj][m] = fmaxf(a[jj], 0.0f);
    }
    __syncthreads();
    {
        float b[8];
        #pragma unroll
        for (int jj = 0; jj < 8; ++jj) b[jj] = bg2[slab * 8 + jj];
        for (int k = 0; k < 64; ++k) {
            float gv = G1[k][m];
            #pragma unroll
            for (int jj = 0; jj < 8; ++jj)
                b[jj] = fmaf(Wg2[(size_t)(slab * 8 + jj) * 64 + k], gv, b[jj]);
        }
        #pragma unroll
        for (int jj = 0; jj < 8; ++jj) G2[slab * 8 + jj][m] = fmaxf(b[jj], 0.0f);
    }
    __syncthreads();
    if (t < 64 && m0 + t < N_NODES_C) {
        float s = bg3[0];
        #pragma unroll
        for (int k = 0; k < 32; ++k) s = fmaf(Wg3[k], G2[k][t], s);
        gate[m0 + t] = s;
    }
}

// ---------------- Per-graph softmax + attention + embedding ----------------

__global__ __launch_bounds__(256) void graph_attn(
    const float* __restrict__ gate, const int* __restrict__ grp,
    const float* __restrict__ h3, float* __restrict__ att_out,
    float* __restrict__ emb)
{
    int g = blockIdx.x;
    int t = threadIdx.x;
    int s = grp[g], e = grp[g + 1];
    __shared__ float red[256];
    __shared__ float attb[256];

    float m = -3.4e38f;
    for (int i = s + t; i < e; i += 256) m = fmaxf(m, gate[i]);
    red[t] = m;
    __syncthreads();
    #pragma unroll
    for (int off = 128; off >= 1; off >>= 1) {
        if (t < off) red[t] = fmaxf(red[t], red[t + off]);
        __syncthreads();
    }
    m = red[0];
    __syncthreads();

    float sum = 0.0f;
    for (int i = s + t; i < e; i += 256) sum += __expf(gate[i] - m);
    red[t] = sum;
    __syncthreads();
    #pragma unroll
    for (int off = 128; off >= 1; off >>= 1) {
        if (t < off) red[t] += red[t + off];
        __syncthreads();
    }
    float scale = 1.0f / (red[0] + 1e-16f);
    __syncthreads();

    int j = t & 127;
    int half = t >> 7;
    float acc = 0.0f;
    for (int base = s; base < e; base += 256) {
        int i = base + t;
        float a = 0.0f;
        if (i < e) {
            a = __expf(gate[i] - m) * scale;
            att_out[i] = a;
        }
        attb[t] = a;
        __syncthreads();
        int cnt = e - base; if (cnt > 256) cnt = 256;
        for (int r = half; r < cnt; r += 2)
            acc = fmaf(attb[r], h3[(size_t)(base + r) * HDIM_C + j], acc);
        __syncthreads();
    }
    red[t] = acc;
    __syncthreads();
    if (t < 128) emb[(size_t)g * 128 + t] = red[t] + red[t + 128];
}

// ---------------- Final MLP ----------------

__global__ __launch_bounds__(256) void final_mlp(
    const float* __restrict__ emb, const float* __restrict__ us, const float* __restrict__ ud,
    const float* __restrict__ Wl1, const float* __restrict__ bl1,
    const float* __restrict__ Wl2, const float* __restrict__ bl2,
    const float* __restrict__ Wl3, const float* __restrict__ bl3,
    const float* __restrict__ Wl, const float* __restrict__ bl,
    float* __restrict__ out5)
{
    int g = blockIdx.x;
    int t = threadIdx.x;
    __shared__ float e2[256], o1[256], o2[128], o3[64], o4[4];
    if (t < 128) e2[t] = emb[(size_t)g * 128 + t];
    else if (t < 192) e2[t] = us[(size_t)g * 64 + (t - 128)];
    else e2[t] = ud[(size_t)g * 64 + (t - 192)];
    __syncthreads();
    {
        float s = bl1[t];
        const float* wr = Wl1 + (size_t)t * 256;
        #pragma unroll 8
        for (int k = 0; k < 256; k++) s = fmaf(wr[k], e2[k], s);
        o1[t] = fmaxf(s, 0.0f);
    }
    __syncthreads();
    if (t < 128) {
        float s = bl2[t];
        const float* wr = Wl2 + (size_t)t * 256;
        #pragma unroll 8
        for (int k = 0; k < 256; k++) s = fmaf(wr[k], o1[k], s);
        o2[t] = fmaxf(s, 0.0f);
    }
    __syncthreads();
    if (t < 64) {
        float s = bl3[t];
        const float* wr = Wl3 + (size_t)t * 128;
        #pragma unroll 8
        for (int k = 0; k < 128; k++) s = fmaf(wr[k], o2[k], s);
        o3[t] = fmaxf(s, 0.0f);
    }
    __syncthreads();
    if (t < 4) {
        float s = bl[t];
        const float* wr = Wl + (size_t)t * 64;
        #pragma unroll 8
        for (int k = 0; k < 64; k++) s = fmaf(wr[k], o3[k], s);
        o4[t] = s;
    }
    __syncthreads();
    if (t < 5) {
        float v = (t < 4) ? o4[t] : (o4[0] + o4[1] + o4[2] + o4[3]);
        out5[(size_t)g * 5 + t] = v;
    }
}

// ---------------- launch ----------------

extern "C" void kernel_launch(void* const* d_in, const int* in_sizes, int n_in,
                              void* d_out, int out_size, void* d_ws, size_t ws_size,
                              hipStream_t stream) {
    const float* x       = (const float*)d_in[0];
    const float* ea      = (const float*)d_in[1];
    const float* u_soap  = (const float*)d_in[2];
    const float* u_dimer = (const float*)d_in[3];
    const float* W1n = (const float*)d_in[4];   const float* b1n = (const float*)d_in[5];
    const float* W1r = (const float*)d_in[6];   const float* b1r = (const float*)d_in[7];
    const float* W2n = (const float*)d_in[8];   const float* b2n = (const float*)d_in[9];
    const float* W2r = (const float*)d_in[10];  const float* b2r = (const float*)d_in[11];
    const float* W3n = (const float*)d_in[12];  const float* b3n = (const float*)d_in[13];
    const float* W3r = (const float*)d_in[14];  const float* b3r = (const float*)d_in[15];
    const float* Wg1 = (const float*)d_in[16];  const float* bg1 = (const float*)d_in[17];
    const float* Wg2 = (const float*)d_in[18];  const float* bg2 = (const float*)d_in[19];
    const float* Wg3 = (const float*)d_in[20];  const float* bg3 = (const float*)d_in[21];
    const float* Wl1 = (const float*)d_in[22];  const float* bl1 = (const float*)d_in[23];
    const float* Wl2 = (const float*)d_in[24];  const float* bl2 = (const float*)d_in[25];
    const float* Wl3 = (const float*)d_in[26];  const float* bl3 = (const float*)d_in[27];
    const float* Wl  = (const float*)d_in[28];  const float* bl  = (const float*)d_in[29];
    const int* eidx  = (const int*)d_in[30];
    const int* batch = (const int*)d_in[31];
    const int* src = eidx;  // row 0 of edge_index

    float* out5 = (float*)d_out;
    float* att  = out5 + (size_t)N_GRAPHS_C * 5;

    char* p = (char*)d_ws;
    size_t off = 0;
    auto alloc = [&](size_t bytes) -> void* {
        void* r = p + off;
        off += (bytes + 255) & ~(size_t)255;
        return r;
    };
    int* cnt     = (int*)alloc((size_t)N_NODES_C * 4);
    int* rowptr  = (int*)alloc((size_t)(N_NODES_C + 1) * 4);
    int* work    = (int*)alloc((size_t)N_NODES_C * 4);
    int* eord    = (int*)alloc((size_t)(N_EDGES_C + 64) * 4);
    int* grp     = (int*)alloc((size_t)(N_GRAPHS_C + 1) * 4);
    int2* nmeta  = (int2*)alloc((size_t)N_NODES_C * 8);
    float* gate  = (float*)alloc((size_t)N_NODES_C * 4);
    float* emb   = (float*)alloc((size_t)N_GRAPHS_C * 128 * 4);
    float* bufP  = (float*)alloc((size_t)N_NODES_C * HDIM_C * 4);
    float* bufQ  = (float*)alloc((size_t)N_NODES_C * HDIM_C * 4);
    float* bufR  = (float*)alloc((size_t)N_NODES_C * HDIM_C * 4);
    _Float16* EAh = (_Float16*)alloc((size_t)N_EDGES_C * 48 * 2);

    hipMemsetAsync(cnt, 0, (size_t)N_NODES_C * 4, stream);

    int eblocks = (N_EDGES_C + 255) / 256;
    // coalesced f32->f16 conversion (edge order, no permutation)
    ea2h<<<(N_EDGES_C + 63) / 64, 256, 0, stream>>>(ea, EAh);
    hist_kernel<<<eblocks, 256, 0, stream>>>(src, cnt);
    scan_kernel<<<1, 1024, 0, stream>>>(cnt, rowptr, work);
    scatter_kernel<<<eblocks, 256, 0, stream>>>(src, work, eord);
    graph_misc<<<(N_NODES_C + 255) / 256, 256, 0, stream>>>(rowptr, batch, nmeta, grp);

    dim3 ng((N_NODES_C + 63) / 64, 2);
    int egrid = 2048;

    // L1: x -> (Base=P, Root=Q); edge writes h1 into P
    node_gemm<<<ng, 256, 0, stream>>>(x, IN_DIM_C, W1n, IN_DIM_C + EDGE_DIM_C, b1n, W1r, b1r, bufP, bufQ);
    edge_mfma<<<egrid, 256, 0, stream>>>(EAh, eord, nmeta, bufP, bufQ, W1n, IN_DIM_C, IN_DIM_C + EDGE_DIM_C, bufP);
    // L2: P -> (Base=Q, Root=R); edge writes h2 into Q
    node_gemm<<<ng, 256, 0, stream>>>(bufP, HDIM_C, W2n, HDIM_C + EDGE_DIM_C, b2n, W2r, b2r, bufQ, bufR);
    edge_mfma<<<egrid, 256, 0, stream>>>(EAh, eord, nmeta, bufQ, bufR, W2n, HDIM_C, HDIM_C + EDGE_DIM_C, bufQ);
    // L3: Q -> (Base=P, Root=R); edge writes h3 into P
    node_gemm<<<ng, 256, 0, stream>>>(bufQ, HDIM_C, W3n, HDIM_C + EDGE_DIM_C, b3n, W3r, b3r, bufP, bufR);
    edge_mfma<<<egrid, 256, 0, stream>>>(EAh, eord, nmeta, bufP, bufR, W3n, HDIM_C, HDIM_C + EDGE_DIM_C, bufP);

    gate_kernel<<<(N_NODES_C + 63) / 64, 256, 0, stream>>>(bufP, Wg1, bg1, Wg2, bg2, Wg3, bg3, gate);
    graph_attn<<<N_GRAPHS_C, 256, 0, stream>>>(gate, grp, bufP, att, emb);
    final_mlp<<<N_GRAPHS_C, 256, 0, stream>>>(emb, u_soap, u_dimer,
                                              Wl1, bl1, Wl2, bl2, Wl3, bl3, Wl, bl, out5);
}

// Round 3
// 1626.337 us; speedup vs baseline: 1.0658x; 1.0658x over previous
//
#include <hip/hip_runtime.h>
#include <cstdint>
#include <cstddef>

#define N_NODES_C 50000
#define N_EDGES_C 1600000
#define N_GRAPHS_C 128
#define EDGE_DIM_C 43
#define IN_DIM_C 35
#define HDIM_C 128

typedef _Float16 f16x8 __attribute__((ext_vector_type(8)));
typedef float f32x4 __attribute__((ext_vector_type(4)));

__device__ __forceinline__ float fast_tanh(float x) {
    float xc = fminf(9.0f, fmaxf(-9.0f, x));
    float t = __expf(2.0f * xc);
    return (t - 1.0f) * __builtin_amdgcn_rcpf(t + 1.0f);
}

// 2*log2(e)
#define TANH_K 2.8853900817779268f

__device__ __forceinline__ float exp2f_fast(float x) {
#if __has_builtin(__builtin_amdgcn_exp2f)
    return __builtin_amdgcn_exp2f(x);
#else
    return __expf(x * 0.69314718055994531f);
#endif
}

// tanh from pre-scaled argument a = 2*log2e*x:
// tanh(x) = 1 - 2/(2^a + 1). Saturates correctly without clamping.
__device__ __forceinline__ float tanh_from_arg(float a) {
    float t = exp2f_fast(a);
    return fmaf(-2.0f, __builtin_amdgcn_rcpf(t + 1.0f), 1.0f);
}

// ---------------- CSR build ----------------

__global__ __launch_bounds__(256) void hist_kernel(const int* __restrict__ src,
                                                   int* __restrict__ cnt) {
    int i = blockIdx.x * 256 + threadIdx.x;
    if (i < N_EDGES_C) atomicAdd(&cnt[src[i]], 1);
}

// single-array scan: rowptr (edge CSR); work = copy for the scatter pass
__global__ __launch_bounds__(1024) void scan_kernel(const int* __restrict__ cnt,
                                                    int* __restrict__ rowptr,
                                                    int* __restrict__ work) {
    __shared__ int wsum[16];
    __shared__ int carry;
    int t = threadIdx.x;
    int lane = t & 63, wid = t >> 6;
    if (t == 0) carry = 0;
    __syncthreads();
    for (int base = 0; base < N_NODES_C; base += 4096) {
        int i0 = base + t * 4;
        int v[4];
        #pragma unroll
        for (int j = 0; j < 4; ++j) {
            int i = i0 + j;
            v[j] = (i < N_NODES_C) ? cnt[i] : 0;
        }
        int pv[4];
        pv[0] = 0;
        #pragma unroll
        for (int j = 1; j < 4; ++j) pv[j] = pv[j-1] + v[j-1];
        int tot = pv[3] + v[3];
        int x = tot;
        #pragma unroll
        for (int off = 1; off < 64; off <<= 1) {
            int xx = __shfl_up(x, off, 64);
            if (lane >= off) x += xx;
        }
        if (lane == 63) wsum[wid] = x;
        __syncthreads();
        if (wid == 0) {
            int wa = (lane < 16) ? wsum[lane] : 0;
            #pragma unroll
            for (int off = 1; off < 16; off <<= 1) {
                int aa = __shfl_up(wa, off, 64);
                if (lane >= off) wa += aa;
            }
            if (lane < 16) wsum[lane] = wa;
        }
        __syncthreads();
        int ex = carry + (wid ? wsum[wid - 1] : 0) + x - tot;
        #pragma unroll
        for (int j = 0; j < 4; ++j) {
            int i = i0 + j;
            if (i < N_NODES_C) {
                int rv = ex + pv[j];
                rowptr[i] = rv; work[i] = rv;
            }
        }
        int totAll = wsum[15];
        __syncthreads();
        if (t == 0) carry += totAll;
        __syncthreads();
    }
    if (t == 0) rowptr[N_NODES_C] = carry;
}

// builds eord: edge ids sorted by (src node, arrival order) — CSR order
__global__ __launch_bounds__(256) void scatter_kernel(const int* __restrict__ src,
                                                      int* __restrict__ work,
                                                      int* __restrict__ eord) {
    int i = blockIdx.x * 256 + threadIdx.x;
    if (i < N_EDGES_C) {
        int s = src[i];
        int pos = atomicAdd(&work[s], 1);
        eord[pos] = i;
    }
}

// merged: graph bounds (binary search) + per-node meta {deg, rowptr}
__global__ __launch_bounds__(256) void graph_misc(const int* __restrict__ rowptr,
                                                  const int* __restrict__ batch,
                                                  int2* __restrict__ nmeta,
                                                  int* __restrict__ grp) {
    int i = blockIdx.x * 256 + threadIdx.x;
    if (i < N_NODES_C) {
        int rp = rowptr[i];
        int deg = rowptr[i + 1] - rp;
        nmeta[i] = make_int2(deg, rp);
    }
    if (i <= N_GRAPHS_C) {
        int lo = 0, hi = N_NODES_C;
        while (lo < hi) {
            int mid = (lo + hi) >> 1;
            if (batch[mid] < i) lo = mid + 1; else hi = mid;
        }
        grp[i] = lo;
    }
}

// STREAMING f32->f16 conversion in EDGE ORDER: fully coalesced both sides.
// Row = 48 halfs (96 B, 16B-aligned); cols 43..47 zeroed.
__global__ __launch_bounds__(256) void ea2h(const float* __restrict__ EA,
                                            _Float16* __restrict__ EAh) {
    int t = threadIdx.x;
    int e = blockIdx.x * 64 + (t >> 2);
    int q = t & 3;
    if (e >= N_EDGES_C) return;
    const float* pe = EA + (size_t)e * EDGE_DIM_C;
    unsigned int pk[6];
    #pragma unroll
    for (int jj = 0; jj < 6; ++jj) {
        int c0 = q * 12 + 2 * jj;
        float v0 = (c0 < EDGE_DIM_C) ? pe[c0] : 0.0f;
        float v1 = (c0 + 1 < EDGE_DIM_C) ? pe[c0 + 1] : 0.0f;
        unsigned short h0 = __builtin_bit_cast(unsigned short, (_Float16)v0);
        unsigned short h1 = __builtin_bit_cast(unsigned short, (_Float16)v1);
        pk[jj] = (unsigned int)h0 | ((unsigned int)h1 << 16);
    }
    unsigned int* outp = (unsigned int*)(EAh + (size_t)e * 48 + q * 12);
    *(uint2*)(outp)     = make_uint2(pk[0], pk[1]);
    *(uint2*)(outp + 2) = make_uint2(pk[2], pk[3]);
    *(uint2*)(outp + 4) = make_uint2(pk[4], pk[5]);
}

// ---------------- Node GEMM (Base = A@Wx.T+bn ; Root = tanh(A@Wr.T+br)) ----------------

#define BKN 32
__global__ __launch_bounds__(256) void node_gemm(
    const float* __restrict__ A, int K,
    const float* __restrict__ Wn, int ldn, const float* __restrict__ bn,
    const float* __restrict__ Wr, const float* __restrict__ br,
    float* __restrict__ Base, float* __restrict__ Root)
{
    __shared__ float At[BKN][64];
    __shared__ float Bw[BKN][128];
    int t = threadIdx.x;
    int z = blockIdx.y;
    const float* W = z ? Wr : Wn;
    int ldW = z ? K : ldn;
    const float* bias = z ? br : bn;
    float* Out = z ? Root : Base;

    int m0 = blockIdx.x * 64;
    int tn4 = (t % 32) * 4;
    int tm8 = (t / 32) * 8;
    float acc[8][4];
    #pragma unroll
    for (int a = 0; a < 8; a++)
        #pragma unroll
        for (int b = 0; b < 4; b++) acc[a][b] = 0.0f;

    int nkc = (K + BKN - 1) / BKN;
    for (int c = 0; c < nkc; c++) {
        int kc = c * BKN;
        {
            int m_l = t >> 2;
            int q = t & 3;
            int m = m0 + m_l;
            #pragma unroll
            for (int ii = 0; ii < 8; ii++) {
                int kk = q * 8 + ii;
                int k = kc + kk;
                float v = 0.0f;
                if (m < N_NODES_C && k < K) v = A[(size_t)m * K + k];
                At[kk][m_l] = v;
            }
        }
        {
            int j = t % 128;
            int kg2 = t / 128;
            #pragma unroll
            for (int ii = 0; ii < 16; ii++) {
                int kk = kg2 * 16 + ii;
                int k = kc + kk;
                float v = 0.0f;
                if (k < K) v = W[(size_t)j * ldW + k];
                Bw[kk][j] = v;
            }
        }
        __syncthreads();
        #pragma unroll
        for (int kk = 0; kk < BKN; kk++) {
            float a[8], b[4];
            #pragma unroll
            for (int mi = 0; mi < 8; mi++) a[mi] = At[kk][tm8 + mi];
            #pragma unroll
            for (int ni = 0; ni < 4; ni++) b[ni] = Bw[kk][tn4 + ni];
            #pragma unroll
            for (int mi = 0; mi < 8; mi++)
                #pragma unroll
                for (int ni = 0; ni < 4; ni++)
                    acc[mi][ni] = fmaf(a[mi], b[ni], acc[mi][ni]);
        }
        __syncthreads();
    }

    float4 bv = *(const float4*)&bias[tn4];
    #pragma unroll
    for (int mi = 0; mi < 8; mi++) {
        int m = m0 + tm8 + mi;
        if (m < N_NODES_C) {
            float4 o;
            o.x = acc[mi][0] + bv.x;
            o.y = acc[mi][1] + bv.y;
            o.z = acc[mi][2] + bv.z;
            o.w = acc[mi][3] + bv.w;
            if (z) { o.x = fast_tanh(o.x); o.y = fast_tanh(o.y); o.z = fast_tanh(o.z); o.w = fast_tanh(o.w); }
            *(float4*)&Out[(size_t)m * HDIM_C + tn4] = o;
        }
    }
}

// ---------------- MFMA edge conv: wave-per-node, cross-node pipelined gather ----------------

__global__ __launch_bounds__(256) void edge_mfma(
    const _Float16* __restrict__ EAh, const int* __restrict__ eord,
    const int2* __restrict__ nmeta,
    const float* __restrict__ Base, const float* __restrict__ Root,
    const float* __restrict__ Wfull, int colOff, int ldW,
    float* __restrict__ Hout)
{
    int t = threadIdx.x;
    int lane = t & 63, wid = t >> 6;
    int l15 = lane & 15, quad = lane >> 4;

    // B fragments: weights held in VGPRs for the whole kernel
    f16x8 bf[8][2];
    #pragma unroll
    for (int nt = 0; nt < 8; ++nt) {
        const float* wr = Wfull + (size_t)(nt * 16 + l15) * ldW + colOff;
        #pragma unroll
        for (int kt = 0; kt < 2; ++kt) {
            f16x8 b;
            #pragma unroll
            for (int j = 0; j < 8; ++j) {
                int k = kt * 32 + quad * 8 + j;
                float v = (k < EDGE_DIM_C) ? wr[k] : 0.0f;
                b[j] = (_Float16)v;
            }
            bf[nt][kt] = b;
        }
    }

    bool useA1 = (quad < 2);
    int off0 = quad * 8;                 // halfs, k 0..31
    int off1 = 32 + ((quad & 1) * 8);    // halfs, k 32..47 (quads 0,1)
    int rbase = quad * 4;

    int nstride = gridDim.x * 4;
    int n = blockIdx.x * 4 + wid;
    if (n >= N_NODES_C) return;

    f16x8 zz8 = {};
    f16x8 a0 = zz8, a1 = zz8;
    bool pf = false;                     // a0/a1 hold group 0 of current node?
    int2 nm = nmeta[n];

    while (true) {
        int n2 = n + nstride;
        bool has2 = (n2 < N_NODES_C);
        int2 nm2 = make_int2(0, 0);
        if (has2) nm2 = nmeta[n2];

        int deg = nm.x, rp = nm.y;
        int ngr = (deg + 15) >> 4;

        const float* bp = Base + (size_t)n * HDIM_C;
        float b2[8];
        #pragma unroll
        for (int nt = 0; nt < 8; ++nt) b2[nt] = TANH_K * bp[nt * 16 + l15];

        float cs[8];
        #pragma unroll
        for (int nt = 0; nt < 8; ++nt) cs[nt] = 0.0f;

        if (ngr > 0) {
            if (!pf) {   // wave-uniform; first iteration or after a deg==0 gap
                a0 = zz8; a1 = zz8;
                if (l15 < deg) {
                    int e0 = eord[rp + l15];
                    const _Float16* ap = EAh + (size_t)e0 * 48;
                    a0 = *(const f16x8*)(ap + off0);
                    if (useA1) a1 = *(const f16x8*)(ap + off1);
                }
            }
            for (int gi = 0; gi < ngr; ++gi) {
                // prefetch: next group of this node, or group 0 of next node
                f16x8 p0 = zz8, p1 = zz8;
                if (gi + 1 < ngr) {
                    int rn = (gi + 1) * 16 + l15;
                    if (rn < deg) {
                        int en = eord[rp + rn];
                        const _Float16* ap = EAh + (size_t)en * 48;
                        p0 = *(const f16x8*)(ap + off0);
                        if (useA1) p1 = *(const f16x8*)(ap + off1);
                    }
                } else if (has2 && nm2.x > 0) {
                    if (l15 < nm2.x) {
                        int en = eord[nm2.y + l15];
                        const _Float16* ap = EAh + (size_t)en * 48;
                        p0 = *(const f16x8*)(ap + off0);
                        if (useA1) p1 = *(const f16x8*)(ap + off1);
                    }
                }

                int valid = deg - gi * 16; if (valid > 16) valid = 16;
                f32x4 acc[8];
                #pragma unroll
                for (int nt = 0; nt < 8; ++nt) {
                    f32x4 zz = {0.f, 0.f, 0.f, 0.f};
                    acc[nt] = __builtin_amdgcn_mfma_f32_16x16x32_f16(a0, bf[nt][0], zz, 0, 0, 0);
                    acc[nt] = __builtin_amdgcn_mfma_f32_16x16x32_f16(a1, bf[nt][1], acc[nt], 0, 0, 0);
                }
                if (valid == 16) {       // full group: no masking (wave-uniform branch)
                    #pragma unroll
                    for (int nt = 0; nt < 8; ++nt) {
                        float s = tanh_from_arg(fmaf(TANH_K, acc[nt][0], b2[nt]));
                        s += tanh_from_arg(fmaf(TANH_K, acc[nt][1], b2[nt]));
                        s += tanh_from_arg(fmaf(TANH_K, acc[nt][2], b2[nt]));
                        s += tanh_from_arg(fmaf(TANH_K, acc[nt][3], b2[nt]));
                        cs[nt] += s;
                    }
                } else {                 // tail group: mask invalid rows
                    int rq = valid - rbase;
                    #pragma unroll
                    for (int nt = 0; nt < 8; ++nt) {
                        #pragma unroll
                        for (int r = 0; r < 4; ++r) {
                            float v = tanh_from_arg(fmaf(TANH_K, acc[nt][r], b2[nt]));
                            cs[nt] += (r < rq) ? v : 0.0f;
                        }
                    }
                }
                a0 = p0; a1 = p1;
            }
            pf = has2 && (nm2.x > 0);
        } else {
            pf = false;
        }

        #pragma unroll
        for (int nt = 0; nt < 8; ++nt) {
            cs[nt] += __shfl_xor(cs[nt], 16, 64);
            cs[nt] += __shfl_xor(cs[nt], 32, 64);
        }
        float v0, v1;
        if (quad == 0)      { v0 = cs[0]; v1 = cs[1]; }
        else if (quad == 1) { v0 = cs[2]; v1 = cs[3]; }
        else if (quad == 2) { v0 = cs[4]; v1 = cs[5]; }
        else                { v0 = cs[6]; v1 = cs[7]; }
        int c0 = quad * 32 + l15;
        size_t rowb = (size_t)n * HDIM_C;
        Hout[rowb + c0]      = Root[rowb + c0] + v0;
        Hout[rowb + c0 + 16] = Root[rowb + c0 + 16] + v1;

        if (!has2) break;
        n = n2; nm = nm2;
    }
}

// ---------------- Gate MLP as tiled GEMM: 64 nodes/block, 128->64->32->1 ----------------

__global__ __launch_bounds__(256) void gate_kernel(
    const float* __restrict__ h,
    const float* __restrict__ Wg1, const float* __restrict__ bg1,
    const float* __restrict__ Wg2, const float* __restrict__ bg2,
    const float* __restrict__ Wg3, const float* __restrict__ bg3,
    float* __restrict__ gate)
{
    __shared__ float Ht[128][65];
    __shared__ float G1[64][65];
    __shared__ float G2[32][65];
    int t = threadIdx.x;
    int m0 = blockIdx.x * 64;
    #pragma unroll
    for (int ii = 0; ii < 32; ++ii) {
        int flat = ii * 256 + t;
        int k = flat & 127, m = flat >> 7;
        float v = (m0 + m < N_NODES_C) ? h[(size_t)(m0 + m) * HDIM_C + k] : 0.0f;
        Ht[k][m] = v;
    }
    __syncthreads();
    int m = t & 63, slab = t >> 6;
    {
        float a[16];
        #pragma unroll
        for (int jj = 0; jj < 16; ++jj) a[jj] = bg1[slab * 16 + jj];
        for (int k = 0; k < 128; ++k) {
            float hv = Ht[k][m];
            #pragma unroll
            for (int jj = 0; jj < 16; ++jj)
                a[jj] = fmaf(Wg1[(size_t)(slab * 16 + jj) * 128 + k], hv, a[jj]);
        }
        #pragma unroll
        for (int jj = 0; jj < 16; ++jj) G1[slab * 16 + jj][m] = fmaxf(a[jj], 0.0f);
    }
    __syncthreads();
    {
        float b[8];
        #pragma unroll
        for (int jj = 0; jj < 8; ++jj) b[jj] = bg2[slab * 8 + jj];
        for (int k = 0; k < 64; ++k) {
            float gv = G1[k][m];
            #pragma unroll
            for (int jj = 0; jj < 8; ++jj)
                b[jj] = fmaf(Wg2[(size_t)(slab * 8 + jj) * 64 + k], gv, b[jj]);
        }
        #pragma unroll
        for (int jj = 0; jj < 8; ++jj) G2[slab * 8 + jj][m] = fmaxf(b[jj], 0.0f);
    }
    __syncthreads();
    if (t < 64 && m0 + t < N_NODES_C) {
        float s = bg3[0];
        #pragma unroll
        for (int k = 0; k < 32; ++k) s = fmaf(Wg3[k], G2[k][t], s);
        gate[m0 + t] = s;
    }
}

// ---------------- Per-graph softmax + attention + embedding ----------------

__global__ __launch_bounds__(256) void graph_attn(
    const float* __restrict__ gate, const int* __restrict__ grp,
    const float* __restrict__ h3, float* __restrict__ att_out,
    float* __restrict__ emb)
{
    int g = blockIdx.x;
    int t = threadIdx.x;
    int s = grp[g], e = grp[g + 1];
    __shared__ float red[256];
    __shared__ float attb[256];

    float m = -3.4e38f;
    for (int i = s + t; i < e; i += 256) m = fmaxf(m, gate[i]);
    red[t] = m;
    __syncthreads();
    #pragma unroll
    for (int off = 128; off >= 1; off >>= 1) {
        if (t < off) red[t] = fmaxf(red[t], red[t + off]);
        __syncthreads();
    }
    m = red[0];
    __syncthreads();

    float sum = 0.0f;
    for (int i = s + t; i < e; i += 256) sum += __expf(gate[i] - m);
    red[t] = sum;
    __syncthreads();
    #pragma unroll
    for (int off = 128; off >= 1; off >>= 1) {
        if (t < off) red[t] += red[t + off];
        __syncthreads();
    }
    float scale = 1.0f / (red[0] + 1e-16f);
    __syncthreads();

    int j = t & 127;
    int half = t >> 7;
    float acc = 0.0f;
    for (int base = s; base < e; base += 256) {
        int i = base + t;
        float a = 0.0f;
        if (i < e) {
            a = __expf(gate[i] - m) * scale;
            att_out[i] = a;
        }
        attb[t] = a;
        __syncthreads();
        int cnt = e - base; if (cnt > 256) cnt = 256;
        for (int r = half; r < cnt; r += 2)
            acc = fmaf(attb[r], h3[(size_t)(base + r) * HDIM_C + j], acc);
        __syncthreads();
    }
    red[t] = acc;
    __syncthreads();
    if (t < 128) emb[(size_t)g * 128 + t] = red[t] + red[t + 128];
}

// ---------------- Final MLP ----------------

__global__ __launch_bounds__(256) void final_mlp(
    const float* __restrict__ emb, const float* __restrict__ us, const float* __restrict__ ud,
    const float* __restrict__ Wl1, const float* __restrict__ bl1,
    const float* __restrict__ Wl2, const float* __restrict__ bl2,
    const float* __restrict__ Wl3, const float* __restrict__ bl3,
    const float* __restrict__ Wl, const float* __restrict__ bl,
    float* __restrict__ out5)
{
    int g = blockIdx.x;
    int t = threadIdx.x;
    __shared__ float e2[256], o1[256], o2[128], o3[64], o4[4];
    if (t < 128) e2[t] = emb[(size_t)g * 128 + t];
    else if (t < 192) e2[t] = us[(size_t)g * 64 + (t - 128)];
    else e2[t] = ud[(size_t)g * 64 + (t - 192)];
    __syncthreads();
    {
        float s = bl1[t];
        const float* wr = Wl1 + (size_t)t * 256;
        #pragma unroll 8
        for (int k = 0; k < 256; k++) s = fmaf(wr[k], e2[k], s);
        o1[t] = fmaxf(s, 0.0f);
    }
    __syncthreads();
    if (t < 128) {
        float s = bl2[t];
        const float* wr = Wl2 + (size_t)t * 256;
        #pragma unroll 8
        for (int k = 0; k < 256; k++) s = fmaf(wr[k], o1[k], s);
        o2[t] = fmaxf(s, 0.0f);
    }
    __syncthreads();
    if (t < 64) {
        float s = bl3[t];
        const float* wr = Wl3 + (size_t)t * 128;
        #pragma unroll 8
        for (int k = 0; k < 128; k++) s = fmaf(wr[k], o2[k], s);
        o3[t] = fmaxf(s, 0.0f);
    }
    __syncthreads();
    if (t < 4) {
        float s = bl[t];
        const float* wr = Wl + (size_t)t * 64;
        #pragma unroll 8
        for (int k = 0; k < 64; k++) s = fmaf(wr[k], o3[k], s);
        o4[t] = s;
    }
    __syncthreads();
    if (t < 5) {
        float v = (t < 4) ? o4[t] : (o4[0] + o4[1] + o4[2] + o4[3]);
        out5[(size_t)g * 5 + t] = v;
    }
}

// ---------------- launch ----------------

extern "C" void kernel_launch(void* const* d_in, const int* in_sizes, int n_in,
                              void* d_out, int out_size, void* d_ws, size_t ws_size,
                              hipStream_t stream) {
    const float* x       = (const float*)d_in[0];
    const float* ea      = (const float*)d_in[1];
    const float* u_soap  = (const float*)d_in[2];
    const float* u_dimer = (const float*)d_in[3];
    const float* W1n = (const float*)d_in[4];   const float* b1n = (const float*)d_in[5];
    const float* W1r = (const float*)d_in[6];   const float* b1r = (const float*)d_in[7];
    const float* W2n = (const float*)d_in[8];   const float* b2n = (const float*)d_in[9];
    const float* W2r = (const float*)d_in[10];  const float* b2r = (const float*)d_in[11];
    const float* W3n = (const float*)d_in[12];  const float* b3n = (const float*)d_in[13];
    const float* W3r = (const float*)d_in[14];  const float* b3r = (const float*)d_in[15];
    const float* Wg1 = (const float*)d_in[16];  const float* bg1 = (const float*)d_in[17];
    const float* Wg2 = (const float*)d_in[18];  const float* bg2 = (const float*)d_in[19];
    const float* Wg3 = (const float*)d_in[20];  const float* bg3 = (const float*)d_in[21];
    const float* Wl1 = (const float*)d_in[22];  const float* bl1 = (const float*)d_in[23];
    const float* Wl2 = (const float*)d_in[24];  const float* bl2 = (const float*)d_in[25];
    const float* Wl3 = (const float*)d_in[26];  const float* bl3 = (const float*)d_in[27];
    const float* Wl  = (const float*)d_in[28];  const float* bl  = (const float*)d_in[29];
    const int* eidx  = (const int*)d_in[30];
    const int* batch = (const int*)d_in[31];
    const int* src = eidx;  // row 0 of edge_index

    float* out5 = (float*)d_out;
    float* att  = out5 + (size_t)N_GRAPHS_C * 5;

    char* p = (char*)d_ws;
    size_t off = 0;
    auto alloc = [&](size_t bytes) -> void* {
        void* r = p + off;
        off += (bytes + 255) & ~(size_t)255;
        return r;
    };
    int* cnt     = (int*)alloc((size_t)N_NODES_C * 4);
    int* rowptr  = (int*)alloc((size_t)(N_NODES_C + 1) * 4);
    int* work    = (int*)alloc((size_t)N_NODES_C * 4);
    int* eord    = (int*)alloc((size_t)(N_EDGES_C + 64) * 4);
    int* grp     = (int*)alloc((size_t)(N_GRAPHS_C + 1) * 4);
    int2* nmeta  = (int2*)alloc((size_t)N_NODES_C * 8);
    float* gate  = (float*)alloc((size_t)N_NODES_C * 4);
    float* emb   = (float*)alloc((size_t)N_GRAPHS_C * 128 * 4);
    float* bufP  = (float*)alloc((size_t)N_NODES_C * HDIM_C * 4);
    float* bufQ  = (float*)alloc((size_t)N_NODES_C * HDIM_C * 4);
    float* bufR  = (float*)alloc((size_t)N_NODES_C * HDIM_C * 4);
    _Float16* EAh = (_Float16*)alloc((size_t)N_EDGES_C * 48 * 2);

    hipMemsetAsync(cnt, 0, (size_t)N_NODES_C * 4, stream);

    int eblocks = (N_EDGES_C + 255) / 256;
    ea2h<<<(N_EDGES_C + 63) / 64, 256, 0, stream>>>(ea, EAh);
    hist_kernel<<<eblocks, 256, 0, stream>>>(src, cnt);
    scan_kernel<<<1, 1024, 0, stream>>>(cnt, rowptr, work);
    scatter_kernel<<<eblocks, 256, 0, stream>>>(src, work, eord);
    graph_misc<<<(N_NODES_C + 255) / 256, 256, 0, stream>>>(rowptr, batch, nmeta, grp);

    dim3 ng((N_NODES_C + 63) / 64, 2);
    // 5 blocks/CU at VGPR~100 (5 waves/SIMD) x 256 CUs: one resident round
    int egrid = 1280;

    // L1: x -> (Base=P, Root=Q); edge writes h1 into P
    node_gemm<<<ng, 256, 0, stream>>>(x, IN_DIM_C, W1n, IN_DIM_C + EDGE_DIM_C, b1n, W1r, b1r, bufP, bufQ);
    edge_mfma<<<egrid, 256, 0, stream>>>(EAh, eord, nmeta, bufP, bufQ, W1n, IN_DIM_C, IN_DIM_C + EDGE_DIM_C, bufP);
    // L2: P -> (Base=Q, Root=R); edge writes h2 into Q
    node_gemm<<<ng, 256, 0, stream>>>(bufP, HDIM_C, W2n, HDIM_C + EDGE_DIM_C, b2n, W2r, b2r, bufQ, bufR);
    edge_mfma<<<egrid, 256, 0, stream>>>(EAh, eord, nmeta, bufQ, bufR, W2n, HDIM_C, HDIM_C + EDGE_DIM_C, bufQ);
    // L3: Q -> (Base=P, Root=R); edge writes h3 into P
    node_gemm<<<ng, 256, 0, stream>>>(bufQ, HDIM_C, W3n, HDIM_C + EDGE_DIM_C, b3n, W3r, b3r, bufP, bufR);
    edge_mfma<<<egrid, 256, 0, stream>>>(EAh, eord, nmeta, bufP, bufR, W3n, HDIM_C, HDIM_C + EDGE_DIM_C, bufP);

    gate_kernel<<<(N_NODES_C + 63) / 64, 256, 0, stream>>>(bufP, Wg1, bg1, Wg2, bg2, Wg3, bg3, gate);
    graph_attn<<<N_GRAPHS_C, 256, 0, stream>>>(gate, grp, bufP, att, emb);
    final_mlp<<<N_GRAPHS_C, 256, 0, stream>>>(emb, u_soap, u_dimer,
                                              Wl1, bl1, Wl2, bl2, Wl3, bl3, Wl, bl, out5);
}

// Round 4
// 1573.189 us; speedup vs baseline: 1.1018x; 1.0338x over previous
//
#include <hip/hip_runtime.h>
#include <cstdint>
#include <cstddef>

#define N_NODES_C 50000
#define N_EDGES_C 1600000
#define N_GRAPHS_C 128
#define EDGE_DIM_C 43
#define IN_DIM_C 35
#define HDIM_C 128
#define MAXG_C 150000   // upper bound on #16-edge groups: N + E/16

typedef _Float16 f16x8 __attribute__((ext_vector_type(8)));
typedef float f32x4 __attribute__((ext_vector_type(4)));

__device__ __forceinline__ float fast_tanh(float x) {
    float xc = fminf(9.0f, fmaxf(-9.0f, x));
    float t = __expf(2.0f * xc);
    return (t - 1.0f) * __builtin_amdgcn_rcpf(t + 1.0f);
}

// 2*log2(e)
#define TANH_K 2.8853900817779268f

__device__ __forceinline__ float exp2f_fast(float x) {
#if __has_builtin(__builtin_amdgcn_exp2f)
    return __builtin_amdgcn_exp2f(x);
#else
    return __expf(x * 0.69314718055994531f);
#endif
}

// tanh from pre-scaled argument a = 2*log2e*x:
// tanh(x) = 1 - 2/(2^a + 1). Saturates correctly without clamping.
__device__ __forceinline__ float tanh_from_arg(float a) {
    float t = exp2f_fast(a);
    return fmaf(-2.0f, __builtin_amdgcn_rcpf(t + 1.0f), 1.0f);
}

// ---------------- CSR build ----------------

__global__ __launch_bounds__(256) void hist_kernel(const int* __restrict__ src,
                                                   int* __restrict__ cnt) {
    int i = blockIdx.x * 256 + threadIdx.x;
    if (i < N_EDGES_C) atomicAdd(&cnt[src[i]], 1);
}

// dual scan: rowptr (edge CSR) and growptr (16-edge group index)
__global__ __launch_bounds__(1024) void scan_kernel(const int* __restrict__ cnt,
                                                    int* __restrict__ rowptr,
                                                    int* __restrict__ work,
                                                    int* __restrict__ growptr,
                                                    int* __restrict__ ngroups) {
    __shared__ int wsumA[16], wsumB[16];
    __shared__ int carryA, carryB;
    int t = threadIdx.x;
    int lane = t & 63, wid = t >> 6;
    if (t == 0) { carryA = 0; carryB = 0; }
    __syncthreads();
    for (int base = 0; base < N_NODES_C; base += 4096) {
        int i0 = base + t * 4;
        int v[4], u[4];
        #pragma unroll
        for (int j = 0; j < 4; ++j) {
            int i = i0 + j;
            v[j] = (i < N_NODES_C) ? cnt[i] : 0;
            u[j] = (v[j] + 15) >> 4;
        }
        int pv[4], pu[4];
        pv[0] = 0; pu[0] = 0;
        #pragma unroll
        for (int j = 1; j < 4; ++j) { pv[j] = pv[j-1] + v[j-1]; pu[j] = pu[j-1] + u[j-1]; }
        int tA = pv[3] + v[3], tB = pu[3] + u[3];
        int x = tA, y = tB;
        #pragma unroll
        for (int off = 1; off < 64; off <<= 1) {
            int xx = __shfl_up(x, off, 64);
            int yy = __shfl_up(y, off, 64);
            if (lane >= off) { x += xx; y += yy; }
        }
        if (lane == 63) { wsumA[wid] = x; wsumB[wid] = y; }
        __syncthreads();
        if (wid == 0) {
            int wa = (lane < 16) ? wsumA[lane] : 0;
            int wb = (lane < 16) ? wsumB[lane] : 0;
            #pragma unroll
            for (int off = 1; off < 16; off <<= 1) {
                int aa = __shfl_up(wa, off, 64);
                int bb = __shfl_up(wb, off, 64);
                if (lane >= off) { wa += aa; wb += bb; }
            }
            if (lane < 16) { wsumA[lane] = wa; wsumB[lane] = wb; }
        }
        __syncthreads();
        int exA = carryA + (wid ? wsumA[wid - 1] : 0) + x - tA;
        int exB = carryB + (wid ? wsumB[wid - 1] : 0) + y - tB;
        #pragma unroll
        for (int j = 0; j < 4; ++j) {
            int i = i0 + j;
            if (i < N_NODES_C) {
                int rv = exA + pv[j];
                rowptr[i] = rv; work[i] = rv;
                growptr[i] = exB + pu[j];
            }
        }
        int totA = wsumA[15], totB = wsumB[15];
        __syncthreads();
        if (t == 0) { carryA += totA; carryB += totB; }
        __syncthreads();
    }
    if (t == 0) {
        rowptr[N_NODES_C] = carryA;
        growptr[N_NODES_C] = carryB;
        ngroups[0] = carryB;
    }
}

// builds eord: edge ids sorted by (src node, arrival order) — CSR order
__global__ __launch_bounds__(256) void scatter_kernel(const int* __restrict__ src,
                                                      int* __restrict__ work,
                                                      int* __restrict__ eord) {
    int i = blockIdx.x * 256 + threadIdx.x;
    if (i < N_EDGES_C) {
        int s = src[i];
        int pos = atomicAdd(&work[s], 1);
        eord[pos] = i;
    }
}

// merged: graph bounds (binary search) + per-group descriptors
// gdesc[g] = { node | (valid<<16), first_csr_row }
__global__ __launch_bounds__(256) void graph_misc(const int* __restrict__ rowptr,
                                                  const int* __restrict__ growptr,
                                                  const int* __restrict__ batch,
                                                  int2* __restrict__ gdesc,
                                                  int* __restrict__ grp) {
    int i = blockIdx.x * 256 + threadIdx.x;
    if (i < N_NODES_C) {
        int rp = rowptr[i];
        int deg = rowptr[i + 1] - rp;
        int gp = growptr[i];
        int ngr = (deg + 15) >> 4;
        for (int gi = 0; gi < ngr; ++gi) {
            int valid = deg - gi * 16; if (valid > 16) valid = 16;
            gdesc[gp + gi] = make_int2(i | (valid << 16), rp + gi * 16);
        }
    }
    if (i <= N_GRAPHS_C) {
        int lo = 0, hi = N_NODES_C;
        while (lo < hi) {
            int mid = (lo + hi) >> 1;
            if (batch[mid] < i) lo = mid + 1; else hi = mid;
        }
        grp[i] = lo;
    }
}

// STREAMING f32->f16 conversion in EDGE ORDER: fully coalesced both sides.
// Row = 48 halfs (96 B, 16B-aligned); cols 43..47 zeroed.
__global__ __launch_bounds__(256) void ea2h(const float* __restrict__ EA,
                                            _Float16* __restrict__ EAh) {
    int t = threadIdx.x;
    int e = blockIdx.x * 64 + (t >> 2);
    int q = t & 3;
    if (e >= N_EDGES_C) return;
    const float* pe = EA + (size_t)e * EDGE_DIM_C;
    unsigned int pk[6];
    #pragma unroll
    for (int jj = 0; jj < 6; ++jj) {
        int c0 = q * 12 + 2 * jj;
        float v0 = (c0 < EDGE_DIM_C) ? pe[c0] : 0.0f;
        float v1 = (c0 + 1 < EDGE_DIM_C) ? pe[c0 + 1] : 0.0f;
        unsigned short h0 = __builtin_bit_cast(unsigned short, (_Float16)v0);
        unsigned short h1 = __builtin_bit_cast(unsigned short, (_Float16)v1);
        pk[jj] = (unsigned int)h0 | ((unsigned int)h1 << 16);
    }
    unsigned int* outp = (unsigned int*)(EAh + (size_t)e * 48 + q * 12);
    *(uint2*)(outp)     = make_uint2(pk[0], pk[1]);
    *(uint2*)(outp + 2) = make_uint2(pk[2], pk[3]);
    *(uint2*)(outp + 4) = make_uint2(pk[4], pk[5]);
}

// ---------------- Node GEMM (Base = A@Wx.T+bn ; Root = tanh(A@Wr.T+br)) ----------------

#define BKN 32
__global__ __launch_bounds__(256) void node_gemm(
    const float* __restrict__ A, int K,
    const float* __restrict__ Wn, int ldn, const float* __restrict__ bn,
    const float* __restrict__ Wr, const float* __restrict__ br,
    float* __restrict__ Base, float* __restrict__ Root)
{
    __shared__ float At[BKN][64];
    __shared__ float Bw[BKN][128];
    int t = threadIdx.x;
    int z = blockIdx.y;
    const float* W = z ? Wr : Wn;
    int ldW = z ? K : ldn;
    const float* bias = z ? br : bn;
    float* Out = z ? Root : Base;

    int m0 = blockIdx.x * 64;
    int tn4 = (t % 32) * 4;
    int tm8 = (t / 32) * 8;
    float acc[8][4];
    #pragma unroll
    for (int a = 0; a < 8; a++)
        #pragma unroll
        for (int b = 0; b < 4; b++) acc[a][b] = 0.0f;

    int nkc = (K + BKN - 1) / BKN;
    for (int c = 0; c < nkc; c++) {
        int kc = c * BKN;
        {
            int m_l = t >> 2;
            int q = t & 3;
            int m = m0 + m_l;
            #pragma unroll
            for (int ii = 0; ii < 8; ii++) {
                int kk = q * 8 + ii;
                int k = kc + kk;
                float v = 0.0f;
                if (m < N_NODES_C && k < K) v = A[(size_t)m * K + k];
                At[kk][m_l] = v;
            }
        }
        {
            int j = t % 128;
            int kg2 = t / 128;
            #pragma unroll
            for (int ii = 0; ii < 16; ii++) {
                int kk = kg2 * 16 + ii;
                int k = kc + kk;
                float v = 0.0f;
                if (k < K) v = W[(size_t)j * ldW + k];
                Bw[kk][j] = v;
            }
        }
        __syncthreads();
        #pragma unroll
        for (int kk = 0; kk < BKN; kk++) {
            float a[8], b[4];
            #pragma unroll
            for (int mi = 0; mi < 8; mi++) a[mi] = At[kk][tm8 + mi];
            #pragma unroll
            for (int ni = 0; ni < 4; ni++) b[ni] = Bw[kk][tn4 + ni];
            #pragma unroll
            for (int mi = 0; mi < 8; mi++)
                #pragma unroll
                for (int ni = 0; ni < 4; ni++)
                    acc[mi][ni] = fmaf(a[mi], b[ni], acc[mi][ni]);
        }
        __syncthreads();
    }

    float4 bv = *(const float4*)&bias[tn4];
    #pragma unroll
    for (int mi = 0; mi < 8; mi++) {
        int m = m0 + tm8 + mi;
        if (m < N_NODES_C) {
            float4 o;
            o.x = acc[mi][0] + bv.x;
            o.y = acc[mi][1] + bv.y;
            o.z = acc[mi][2] + bv.z;
            o.w = acc[mi][3] + bv.w;
            if (z) { o.x = fast_tanh(o.x); o.y = fast_tanh(o.y); o.z = fast_tanh(o.z); o.w = fast_tanh(o.w); }
            *(float4*)&Out[(size_t)m * HDIM_C + tn4] = o;
        }
    }
}

// ---------------- MFMA edge conv: GROUP-parallel, 3-stage pipeline, atomic scatter ----------------
// Each wave grid-strides over 16-edge groups (uniform work). Pipeline:
//   compute group g  |  EAh loads for g+1 (indices ready)  |  eord loads for g+2  |  desc load g+3
// Output: Hout is pre-initialized with Root (node_gemm writes it there);
// per-group column sums are accumulated with HW f32 atomics.

__global__ __launch_bounds__(256) void edge_mfma(
    const _Float16* __restrict__ EAh, const int* __restrict__ eord,
    const int2* __restrict__ gdesc, const int* __restrict__ ngroups,
    const float* __restrict__ Base,
    const float* __restrict__ Wfull, int colOff, int ldW,
    float* __restrict__ Hout)
{
    int t = threadIdx.x;
    int lane = t & 63, wid = t >> 6;
    int l15 = lane & 15, quad = lane >> 4;

    // B fragments: weights held in VGPRs for the whole kernel
    f16x8 bf[8][2];
    #pragma unroll
    for (int nt = 0; nt < 8; ++nt) {
        const float* wr = Wfull + (size_t)(nt * 16 + l15) * ldW + colOff;
        #pragma unroll
        for (int kt = 0; kt < 2; ++kt) {
            f16x8 b;
            #pragma unroll
            for (int j = 0; j < 8; ++j) {
                int k = kt * 32 + quad * 8 + j;
                float v = (k < EDGE_DIM_C) ? wr[k] : 0.0f;
                b[j] = (_Float16)v;
            }
            bf[nt][kt] = b;
        }
    }

    bool useA1 = (quad < 2);
    int off0 = quad * 8;                 // halfs, k 0..31
    int off1 = 32 + ((quad & 1) * 8);    // halfs, k 32..47 (quads 0,1)
    int rbase = quad * 4;

    int NG = ngroups[0];
    int W = gridDim.x * 4;
    int g = blockIdx.x * 4 + wid;
    if (g >= NG) return;

    f16x8 zz8 = {};
    // ---- pipeline prologue ----
    int2 d0 = gdesc[g];
    int2 d1 = (g + W < NG) ? gdesc[g + W] : make_int2(0, 0);
    int2 d2 = (g + 2 * W < NG) ? gdesc[g + 2 * W] : make_int2(0, 0);
    int e0 = (l15 < (d0.x >> 16)) ? eord[d0.y + l15] : -1;
    int e1 = (l15 < (d1.x >> 16)) ? eord[d1.y + l15] : -1;
    f16x8 a0 = zz8, a1 = zz8;
    if (e0 >= 0) {
        const _Float16* ap = EAh + (size_t)e0 * 48;
        a0 = *(const f16x8*)(ap + off0);
        if (useA1) a1 = *(const f16x8*)(ap + off1);
    }

    while (true) {
        int n = d0.x & 0xFFFF;
        int valid = d0.x >> 16;

        // stage 3: descriptor for g+3
        int gn3 = g + 3 * W;
        int2 d3 = (gn3 < NG) ? gdesc[gn3] : make_int2(0, 0);
        // stage 2: eord indices for g+2 (d2 ready)
        int e2 = (l15 < (d2.x >> 16)) ? eord[d2.y + l15] : -1;
        // stage 1: EAh rows for g+1 (e1 ready)
        f16x8 p0 = zz8, p1 = zz8;
        if (e1 >= 0) {
            const _Float16* ap = EAh + (size_t)e1 * 48;
            p0 = *(const f16x8*)(ap + off0);
            if (useA1) p1 = *(const f16x8*)(ap + off1);
        }
        // Base loads for this group (consumed after MFMA -> latency hidden)
        const float* bp = Base + (size_t)n * HDIM_C;
        float b2[8];
        #pragma unroll
        for (int nt = 0; nt < 8; ++nt) b2[nt] = TANH_K * bp[nt * 16 + l15];

        // stage 0: compute
        f32x4 acc[8];
        #pragma unroll
        for (int nt = 0; nt < 8; ++nt) {
            f32x4 zz = {0.f, 0.f, 0.f, 0.f};
            acc[nt] = __builtin_amdgcn_mfma_f32_16x16x32_f16(a0, bf[nt][0], zz, 0, 0, 0);
            acc[nt] = __builtin_amdgcn_mfma_f32_16x16x32_f16(a1, bf[nt][1], acc[nt], 0, 0, 0);
        }
        float cs[8];
        if (valid == 16) {       // full group: no masking (wave-uniform branch)
            #pragma unroll
            for (int nt = 0; nt < 8; ++nt) {
                float s = tanh_from_arg(fmaf(TANH_K, acc[nt][0], b2[nt]));
                s += tanh_from_arg(fmaf(TANH_K, acc[nt][1], b2[nt]));
                s += tanh_from_arg(fmaf(TANH_K, acc[nt][2], b2[nt]));
                s += tanh_from_arg(fmaf(TANH_K, acc[nt][3], b2[nt]));
                cs[nt] = s;
            }
        } else {                 // tail group: mask invalid rows
            int rq = valid - rbase;
            #pragma unroll
            for (int nt = 0; nt < 8; ++nt) {
                float s = 0.0f;
                #pragma unroll
                for (int r = 0; r < 4; ++r) {
                    float v = tanh_from_arg(fmaf(TANH_K, acc[nt][r], b2[nt]));
                    s += (r < rq) ? v : 0.0f;
                }
                cs[nt] = s;
            }
        }

        // quad reduction: sum over the 16 rows
        #pragma unroll
        for (int nt = 0; nt < 8; ++nt) {
            cs[nt] += __shfl_xor(cs[nt], 16, 64);
            cs[nt] += __shfl_xor(cs[nt], 32, 64);
        }
        float v0, v1;
        if (quad == 0)      { v0 = cs[0]; v1 = cs[1]; }
        else if (quad == 1) { v0 = cs[2]; v1 = cs[3]; }
        else if (quad == 2) { v0 = cs[4]; v1 = cs[5]; }
        else                { v0 = cs[6]; v1 = cs[7]; }
        int c0 = quad * 32 + l15;
        float* hp = Hout + (size_t)n * HDIM_C;
        unsafeAtomicAdd(hp + c0, v0);
        unsafeAtomicAdd(hp + c0 + 16, v1);

        g += W;
        if (g >= NG) break;
        d0 = d1; d1 = d2; d2 = d3;
        a0 = p0; a1 = p1;
        e1 = e2;
    }
}

// ---------------- Gate MLP as tiled GEMM: 64 nodes/block, 128->64->32->1 ----------------

__global__ __launch_bounds__(256) void gate_kernel(
    const float* __restrict__ h,
    const float* __restrict__ Wg1, const float* __restrict__ bg1,
    const float* __restrict__ Wg2, const float* __restrict__ bg2,
    const float* __restrict__ Wg3, const float* __restrict__ bg3,
    float* __restrict__ gate)
{
    __shared__ float Ht[128][65];
    __shared__ float G1[64][65];
    __shared__ float G2[32][65];
    int t = threadIdx.x;
    int m0 = blockIdx.x * 64;
    #pragma unroll
    for (int ii = 0; ii < 32; ++ii) {
        int flat = ii * 256 + t;
        int k = flat & 127, m = flat >> 7;
        float v = (m0 + m < N_NODES_C) ? h[(size_t)(m0 + m) * HDIM_C + k] : 0.0f;
        Ht[k][m] = v;
    }
    __syncthreads();
    int m = t & 63, slab = t >> 6;
    {
        float a[16];
        #pragma unroll
        for (int jj = 0; jj < 16; ++jj) a[jj] = bg1[slab * 16 + jj];
        for (int k = 0; k < 128; ++k) {
            float hv = Ht[k][m];
            #pragma unroll
            for (int jj = 0; jj < 16; ++jj)
                a[jj] = fmaf(Wg1[(size_t)(slab * 16 + jj) * 128 + k], hv, a[jj]);
        }
        #pragma unroll
        for (int jj = 0; jj < 16; ++jj) G1[slab * 16 + jj][m] = fmaxf(a[jj], 0.0f);
    }
    __syncthreads();
    {
        float b[8];
        #pragma unroll
        for (int jj = 0; jj < 8; ++jj) b[jj] = bg2[slab * 8 + jj];
        for (int k = 0; k < 64; ++k) {
            float gv = G1[k][m];
            #pragma unroll
            for (int jj = 0; jj < 8; ++jj)
                b[jj] = fmaf(Wg2[(size_t)(slab * 8 + jj) * 64 + k], gv, b[jj]);
        }
        #pragma unroll
        for (int jj = 0; jj < 8; ++jj) G2[slab * 8 + jj][m] = fmaxf(b[jj], 0.0f);
    }
    __syncthreads();
    if (t < 64 && m0 + t < N_NODES_C) {
        float s = bg3[0];
        #pragma unroll
        for (int k = 0; k < 32; ++k) s = fmaf(Wg3[k], G2[k][t], s);
        gate[m0 + t] = s;
    }
}

// ---------------- Per-graph softmax + attention + embedding ----------------

__global__ __launch_bounds__(256) void graph_attn(
    const float* __restrict__ gate, const int* __restrict__ grp,
    const float* __restrict__ h3, float* __restrict__ att_out,
    float* __restrict__ emb)
{
    int g = blockIdx.x;
    int t = threadIdx.x;
    int s = grp[g], e = grp[g + 1];
    __shared__ float red[256];
    __shared__ float attb[256];

    float m = -3.4e38f;
    for (int i = s + t; i < e; i += 256) m = fmaxf(m, gate[i]);
    red[t] = m;
    __syncthreads();
    #pragma unroll
    for (int off = 128; off >= 1; off >>= 1) {
        if (t < off) red[t] = fmaxf(red[t], red[t + off]);
        __syncthreads();
    }
    m = red[0];
    __syncthreads();

    float sum = 0.0f;
    for (int i = s + t; i < e; i += 256) sum += __expf(gate[i] - m);
    red[t] = sum;
    __syncthreads();
    #pragma unroll
    for (int off = 128; off >= 1; off >>= 1) {
        if (t < off) red[t] += red[t + off];
        __syncthreads();
    }
    float scale = 1.0f / (red[0] + 1e-16f);
    __syncthreads();

    int j = t & 127;
    int half = t >> 7;
    float acc = 0.0f;
    for (int base = s; base < e; base += 256) {
        int i = base + t;
        float a = 0.0f;
        if (i < e) {
            a = __expf(gate[i] - m) * scale;
            att_out[i] = a;
        }
        attb[t] = a;
        __syncthreads();
        int cnt = e - base; if (cnt > 256) cnt = 256;
        for (int r = half; r < cnt; r += 2)
            acc = fmaf(attb[r], h3[(size_t)(base + r) * HDIM_C + j], acc);
        __syncthreads();
    }
    red[t] = acc;
    __syncthreads();
    if (t < 128) emb[(size_t)g * 128 + t] = red[t] + red[t + 128];
}

// ---------------- Final MLP ----------------

__global__ __launch_bounds__(256) void final_mlp(
    const float* __restrict__ emb, const float* __restrict__ us, const float* __restrict__ ud,
    const float* __restrict__ Wl1, const float* __restrict__ bl1,
    const float* __restrict__ Wl2, const float* __restrict__ bl2,
    const float* __restrict__ Wl3, const float* __restrict__ bl3,
    const float* __restrict__ Wl, const float* __restrict__ bl,
    float* __restrict__ out5)
{
    int g = blockIdx.x;
    int t = threadIdx.x;
    __shared__ float e2[256], o1[256], o2[128], o3[64], o4[4];
    if (t < 128) e2[t] = emb[(size_t)g * 128 + t];
    else if (t < 192) e2[t] = us[(size_t)g * 64 + (t - 128)];
    else e2[t] = ud[(size_t)g * 64 + (t - 192)];
    __syncthreads();
    {
        float s = bl1[t];
        const float* wr = Wl1 + (size_t)t * 256;
        #pragma unroll 8
        for (int k = 0; k < 256; k++) s = fmaf(wr[k], e2[k], s);
        o1[t] = fmaxf(s, 0.0f);
    }
    __syncthreads();
    if (t < 128) {
        float s = bl2[t];
        const float* wr = Wl2 + (size_t)t * 256;
        #pragma unroll 8
        for (int k = 0; k < 256; k++) s = fmaf(wr[k], o1[k], s);
        o2[t] = fmaxf(s, 0.0f);
    }
    __syncthreads();
    if (t < 64) {
        float s = bl3[t];
        const float* wr = Wl3 + (size_t)t * 128;
        #pragma unroll 8
        for (int k = 0; k < 128; k++) s = fmaf(wr[k], o2[k], s);
        o3[t] = fmaxf(s, 0.0f);
    }
    __syncthreads();
    if (t < 4) {
        float s = bl[t];
        const float* wr = Wl + (size_t)t * 64;
        #pragma unroll 8
        for (int k = 0; k < 64; k++) s = fmaf(wr[k], o3[k], s);
        o4[t] = s;
    }
    __syncthreads();
    if (t < 5) {
        float v = (t < 4) ? o4[t] : (o4[0] + o4[1] + o4[2] + o4[3]);
        out5[(size_t)g * 5 + t] = v;
    }
}

// ---------------- launch ----------------

extern "C" void kernel_launch(void* const* d_in, const int* in_sizes, int n_in,
                              void* d_out, int out_size, void* d_ws, size_t ws_size,
                              hipStream_t stream) {
    const float* x       = (const float*)d_in[0];
    const float* ea      = (const float*)d_in[1];
    const float* u_soap  = (const float*)d_in[2];
    const float* u_dimer = (const float*)d_in[3];
    const float* W1n = (const float*)d_in[4];   const float* b1n = (const float*)d_in[5];
    const float* W1r = (const float*)d_in[6];   const float* b1r = (const float*)d_in[7];
    const float* W2n = (const float*)d_in[8];   const float* b2n = (const float*)d_in[9];
    const float* W2r = (const float*)d_in[10];  const float* b2r = (const float*)d_in[11];
    const float* W3n = (const float*)d_in[12];  const float* b3n = (const float*)d_in[13];
    const float* W3r = (const float*)d_in[14];  const float* b3r = (const float*)d_in[15];
    const float* Wg1 = (const float*)d_in[16];  const float* bg1 = (const float*)d_in[17];
    const float* Wg2 = (const float*)d_in[18];  const float* bg2 = (const float*)d_in[19];
    const float* Wg3 = (const float*)d_in[20];  const float* bg3 = (const float*)d_in[21];
    const float* Wl1 = (const float*)d_in[22];  const float* bl1 = (const float*)d_in[23];
    const float* Wl2 = (const float*)d_in[24];  const float* bl2 = (const float*)d_in[25];
    const float* Wl3 = (const float*)d_in[26];  const float* bl3 = (const float*)d_in[27];
    const float* Wl  = (const float*)d_in[28];  const float* bl  = (const float*)d_in[29];
    const int* eidx  = (const int*)d_in[30];
    const int* batch = (const int*)d_in[31];
    const int* src = eidx;  // row 0 of edge_index

    float* out5 = (float*)d_out;
    float* att  = out5 + (size_t)N_GRAPHS_C * 5;

    char* p = (char*)d_ws;
    size_t off = 0;
    auto alloc = [&](size_t bytes) -> void* {
        void* r = p + off;
        off += (bytes + 255) & ~(size_t)255;
        return r;
    };
    int* cnt     = (int*)alloc((size_t)N_NODES_C * 4);
    int* rowptr  = (int*)alloc((size_t)(N_NODES_C + 1) * 4);
    int* growptr = (int*)alloc((size_t)(N_NODES_C + 1) * 4);
    int* work    = (int*)alloc((size_t)N_NODES_C * 4);
    int* eord    = (int*)alloc((size_t)(N_EDGES_C + 64) * 4);
    int* grp     = (int*)alloc((size_t)(N_GRAPHS_C + 1) * 4);
    int* ngroups = (int*)alloc(256);
    int2* gdesc  = (int2*)alloc((size_t)MAXG_C * 8);
    float* gate  = (float*)alloc((size_t)N_NODES_C * 4);
    float* emb   = (float*)alloc((size_t)N_GRAPHS_C * 128 * 4);
    float* bufA  = (float*)alloc((size_t)N_NODES_C * HDIM_C * 4);
    float* bufB  = (float*)alloc((size_t)N_NODES_C * HDIM_C * 4);
    float* bufC  = (float*)alloc((size_t)N_NODES_C * HDIM_C * 4);
    _Float16* EAh = (_Float16*)alloc((size_t)N_EDGES_C * 48 * 2);

    hipMemsetAsync(cnt, 0, (size_t)N_NODES_C * 4, stream);

    int eblocks = (N_EDGES_C + 255) / 256;
    ea2h<<<(N_EDGES_C + 63) / 64, 256, 0, stream>>>(ea, EAh);
    hist_kernel<<<eblocks, 256, 0, stream>>>(src, cnt);
    scan_kernel<<<1, 1024, 0, stream>>>(cnt, rowptr, work, growptr, ngroups);
    scatter_kernel<<<eblocks, 256, 0, stream>>>(src, work, eord);
    graph_misc<<<(N_NODES_C + 255) / 256, 256, 0, stream>>>(rowptr, growptr, batch, gdesc, grp);

    dim3 ng((N_NODES_C + 63) / 64, 2);
    // 4 blocks/CU (VGPR 65-128 bucket -> 4 waves/SIMD) x 256 CUs: one resident round
    int egrid = 1024;

    // Root is written DIRECTLY into the layer's output buffer; edge_mfma atomically
    // accumulates the neighbor sums on top. Base buffer (A) is reused each layer.
    // L1: x -> Base=A, Root/Out=B
    node_gemm<<<ng, 256, 0, stream>>>(x, IN_DIM_C, W1n, IN_DIM_C + EDGE_DIM_C, b1n, W1r, b1r, bufA, bufB);
    edge_mfma<<<egrid, 256, 0, stream>>>(EAh, eord, gdesc, ngroups, bufA, W1n, IN_DIM_C, IN_DIM_C + EDGE_DIM_C, bufB);
    // L2: B -> Base=A, Root/Out=C
    node_gemm<<<ng, 256, 0, stream>>>(bufB, HDIM_C, W2n, HDIM_C + EDGE_DIM_C, b2n, W2r, b2r, bufA, bufC);
    edge_mfma<<<egrid, 256, 0, stream>>>(EAh, eord, gdesc, ngroups, bufA, W2n, HDIM_C, HDIM_C + EDGE_DIM_C, bufC);
    // L3: C -> Base=A, Root/Out=B
    node_gemm<<<ng, 256, 0, stream>>>(bufC, HDIM_C, W3n, HDIM_C + EDGE_DIM_C, b3n, W3r, b3r, bufA, bufB);
    edge_mfma<<<egrid, 256, 0, stream>>>(EAh, eord, gdesc, ngroups, bufA, W3n, HDIM_C, HDIM_C + EDGE_DIM_C, bufB);

    gate_kernel<<<(N_NODES_C + 63) / 64, 256, 0, stream>>>(bufB, Wg1, bg1, Wg2, bg2, Wg3, bg3, gate);
    graph_attn<<<N_GRAPHS_C, 256, 0, stream>>>(gate, grp, bufB, att, emb);
    final_mlp<<<N_GRAPHS_C, 256, 0, stream>>>(emb, u_soap, u_dimer,
                                              Wl1, bl1, Wl2, bl2, Wl3, bl3, Wl, bl, out5);
}